// Round 7
// baseline (42.817 us; speedup 1.0000x reference)
//
#include <hip/hip_runtime.h>
#include <math.h>

#define KS     3
#define ALPHA  0.1f
#define M      56
#define N      56
#define L      18
#define KK     18
#define PIX    (M * N)        // 3136
#define VEC    (PIX / 4)      // 784 float4 per plane
#define WAVES  4
#define NTHR   (WAVES * 64)   // 256
#define COVER  (L * KS)       // 54
#define CHUNKS 13             // 12 full rounds of 64 lanes + 16-lane tail

typedef float vf4 __attribute__((ext_vector_type(4)));

__device__ __forceinline__ float rmax4(vf4 x) {
    return fmaxf(fmaxf(x.x, x.y), fmaxf(x.z, x.w));
}

__global__ __launch_bounds__(NTHR) void div_block_kernel(
    const float* __restrict__ act,
    const int*   __restrict__ rc,
    const int*   __restrict__ pmask,
    float*       __restrict__ out,
    int planes) {

    const int tid = threadIdx.x;
    const int w   = tid >> 6;           // wave id in block
    const int l   = tid & 63;           // lane id
    const int plane = blockIdx.x * WAVES + w;
    if (plane >= planes) return;        // no barriers anywhere -> safe

    const size_t base = (size_t)plane * PIX;
    const vf4* a4 = (const vf4*)(act + base);
    vf4*       o4 = (vf4*)(out + base);

    // per-wave patch mask in LDS (within-wave RAW only; no __syncthreads)
    __shared__ int smask[WAVES][L * KK];
    int* sm = smask[w];
    for (int s = l; s < L * KK; s += 64)
        sm[s] = pmask[(size_t)plane * (L * KK) + s];

    // ---- PASS 1: streaming transform-store (peak-independent) ----
    // act loads are NONTEMPORAL: don't allocate act in L3, so the 256MB L3
    // can keep the 100MB of output dirty-resident across graph replays
    // (write drain -> HBM mostly disappears). Stores stay normal (allocate).
    float lmax = -INFINITY;
    unsigned cand = 0u;

#pragma unroll
    for (int c = 0; c < CHUNKS; ++c) {
        const int v = l + c * 64;
        if (c < 12 || l < (VEC - 12 * 64)) {   // chunks 0..11 unconditional
            vf4 x = __builtin_nontemporal_load(&a4[v]);
            const float rm = rmax4(x);
            if (rm >= lmax) cand |= (1u << c);
            lmax = fmaxf(lmax, rm);

            const int i    = v / 14;        // row (14 vf4/row; no row crossing)
            const int j0   = (v - i * 14) * 4;
            const int mrow = (i < COVER ? (i / 3) : (L - 1)) * KK;  // clamp
            const int c0   = j0 / 3;
            const int c1   = (j0 + 3) / 3;  // group spans <=2 patch cols
            const int ma   = sm[mrow + (c0 < KK ? c0 : KK - 1)];
            const int mb   = sm[mrow + (c1 < KK ? c1 : KK - 1)];
            const bool inrow = (i < COVER);

            vf4 o;
#pragma unroll
            for (int e = 0; e < 4; ++e) {
                const int j  = j0 + e;
                const int mv = ((j / 3) == c0) ? ma : mb;
                const bool cond = inrow && (j < COVER) && (mv != 0);
                o[e] = cond ? x[e] * ALPHA : x[e];
            }
            o4[v] = o;      // regular store: L3-allocate, stay resident
        }
    }

    // ---- wave butterfly max (no LDS, no barrier) ----
    float peak = lmax;
#pragma unroll
    for (int off = 32; off > 0; off >>= 1)
        peak = fmaxf(peak, __shfl_xor(peak, off, 64));

    // ---- PASS 2: fix-up peak pixels. A lane can hold a peak pixel only if
    // its local max equals the plane peak; within it, only flagged chunks can
    // contain it. Typically 1 lane x 1 chunk -> one L2-hot 16B reload. ----
    if (lmax == peak) {
        // order pass-2 stores after this wave's pass-1 stores (same addresses)
        asm volatile("s_waitcnt vmcnt(0)" ::: "memory");
#pragma unroll
        for (int c = 0; c < CHUNKS; ++c) {
            if ((c < 12 || l < (VEC - 12 * 64)) && (cand & (1u << c))) {
                const int v = l + c * 64;
                vf4 x = a4[v];              // L2-hot, ~1 active lane
#pragma unroll
                for (int e = 0; e < 4; ++e) {
                    if (x[e] == peak) {
                        const size_t p = base + (size_t)(v * 4 + e);
                        out[p] = (rc[p] != 0) ? x[e] * ALPHA : x[e];
                    }
                }
            }
        }
    }
}

extern "C" void kernel_launch(void* const* d_in, const int* in_sizes, int n_in,
                              void* d_out, int out_size, void* d_ws, size_t ws_size,
                              hipStream_t stream) {
    const float* act   = (const float*)d_in[0];
    const int*   rc    = (const int*)d_in[1];
    const int*   pmask = (const int*)d_in[2];
    float*       out   = (float*)d_out;

    const int planes = in_sizes[0] / PIX;               // 32*256 = 8192
    const int blocks = (planes + WAVES - 1) / WAVES;    // 2048
    div_block_kernel<<<blocks, NTHR, 0, stream>>>(act, rc, pmask, out, planes);
}

// Round 8
// 40.321 us; speedup vs baseline: 1.0619x; 1.0619x over previous
//
#include <hip/hip_runtime.h>
#include <math.h>

#define KS     3
#define ALPHA  0.1f
#define M      56
#define N      56
#define L      18
#define KK     18
#define PIX    (M * N)        // 3136
#define VEC    (PIX / 4)      // 784 float4 per plane
#define WAVES  4
#define NTHR   (WAVES * 64)   // 256
#define COVER  (L * KS)       // 54
#define CHUNKS 13             // 12 full rounds of 64 lanes + 16-lane tail

typedef float vf4 __attribute__((ext_vector_type(4)));

__device__ __forceinline__ float rmax4(vf4 x) {
    return fmaxf(fmaxf(x.x, x.y), fmaxf(x.z, x.w));
}

__global__ __launch_bounds__(NTHR) void div_block_kernel(
    const float* __restrict__ act,
    const int*   __restrict__ rc,
    const int*   __restrict__ pmask,
    float*       __restrict__ out,
    int planes) {

    const int tid = threadIdx.x;
    const int w   = tid >> 6;           // wave id in block
    const int l   = tid & 63;           // lane id
    const int plane = blockIdx.x * WAVES + w;
    if (plane >= planes) return;        // no barriers anywhere -> safe

    const size_t base = (size_t)plane * PIX;
    const vf4* a4 = (const vf4*)(act + base);
    vf4*       o4 = (vf4*)(out + base);

    // per-wave patch mask in LDS (within-wave RAW only; no __syncthreads)
    __shared__ int smask[WAVES][L * KK];
    int* sm = smask[w];
    for (int s = l; s < L * KK; s += 64)
        sm[s] = pmask[(size_t)plane * (L * KK) + s];

    // ---- PASS 1: streaming transform-store (peak-independent) ----
    // cand bit c set if chunk c's max >= running max at that time: any chunk
    // containing the final peak is guaranteed flagged (false positives
    // harmless — they rescan and find no hit).
    float lmax = -INFINITY;
    unsigned cand = 0u;

#pragma unroll
    for (int c = 0; c < CHUNKS; ++c) {
        const int v = l + c * 64;
        if (c < 12 || l < (VEC - 12 * 64)) {   // chunks 0..11 unconditional
            vf4 x = a4[v];
            const float rm = rmax4(x);
            if (rm >= lmax) cand |= (1u << c);
            lmax = fmaxf(lmax, rm);

            const int i    = v / 14;        // row (14 vf4/row; no row crossing)
            const int j0   = (v - i * 14) * 4;
            const int mrow = (i < COVER ? (i / 3) : (L - 1)) * KK;  // clamp
            const int c0   = j0 / 3;
            const int c1   = (j0 + 3) / 3;  // group spans <=2 patch cols
            const int ma   = sm[mrow + (c0 < KK ? c0 : KK - 1)];
            const int mb   = sm[mrow + (c1 < KK ? c1 : KK - 1)];
            const bool inrow = (i < COVER);

            vf4 o;
#pragma unroll
            for (int e = 0; e < 4; ++e) {
                const int j  = j0 + e;
                const int mv = ((j / 3) == c0) ? ma : mb;
                const bool cond = inrow && (j < COVER) && (mv != 0);
                o[e] = cond ? x[e] * ALPHA : x[e];
            }
            o4[v] = o;      // regular store: let L3 cache out across replays
        }
    }

    // ---- wave butterfly max (no LDS, no barrier) ----
    float peak = lmax;
#pragma unroll
    for (int off = 32; off > 0; off >>= 1)
        peak = fmaxf(peak, __shfl_xor(peak, off, 64));

    // ---- PASS 2: fix-up peak pixels. A lane can hold a peak pixel only if
    // its local max equals the plane peak; within it, only flagged chunks can
    // contain it. Typically 1 lane x 1 chunk -> one L2-hot 16B reload. ----
    if (lmax == peak) {
        // order pass-2 stores after this wave's pass-1 stores (same addresses)
        asm volatile("s_waitcnt vmcnt(0)" ::: "memory");
#pragma unroll
        for (int c = 0; c < CHUNKS; ++c) {
            if ((c < 12 || l < (VEC - 12 * 64)) && (cand & (1u << c))) {
                const int v = l + c * 64;
                vf4 x = a4[v];              // L2/L3-hot, ~1 active lane
#pragma unroll
                for (int e = 0; e < 4; ++e) {
                    if (x[e] == peak) {
                        const size_t p = base + (size_t)(v * 4 + e);
                        out[p] = (rc[p] != 0) ? x[e] * ALPHA : x[e];
                    }
                }
            }
        }
    }
}

extern "C" void kernel_launch(void* const* d_in, const int* in_sizes, int n_in,
                              void* d_out, int out_size, void* d_ws, size_t ws_size,
                              hipStream_t stream) {
    const float* act   = (const float*)d_in[0];
    const int*   rc    = (const int*)d_in[1];
    const int*   pmask = (const int*)d_in[2];
    float*       out   = (float*)d_out;

    const int planes = in_sizes[0] / PIX;               // 32*256 = 8192
    const int blocks = (planes + WAVES - 1) / WAVES;    // 2048
    div_block_kernel<<<blocks, NTHR, 0, stream>>>(act, rc, pmask, out, planes);
}